// Round 1
// baseline (57.754 us; speedup 1.0000x reference)
//
#include <hip/hip_runtime.h>
#include <math.h>

#define NQ  10
#define DIM 1024
#define NL  4

// ---------------------------------------------------------------------------
// Kernel 1: precompute the 40 Rot matrices (shared across the batch).
// PennyLane Rot = RZ(omega) RY(theta) RZ(phi):
//   m00 = e^{-i(phi+omega)/2} cos(theta/2)
//   m01 = -e^{+i(phi-omega)/2} sin(theta/2)
//   m10 =  e^{-i(phi-omega)/2} sin(theta/2)
//   m11 =  e^{+i(phi+omega)/2} cos(theta/2)
// Layout in d_ws: gate (l,w) -> 4 float2 entries m00,m01,m10,m11.
// ---------------------------------------------------------------------------
__global__ __launch_bounds__(64) void rot_precompute(const float* __restrict__ wts,
                                                     float2* __restrict__ g) {
    int idx = threadIdx.x;
    if (idx < NL * NQ) {
        float phi   = wts[idx * 3 + 0];
        float theta = wts[idx * 3 + 1];
        float omega = wts[idx * 3 + 2];
        float st, ct; sincosf(0.5f * theta, &st, &ct);
        float sp, cp; sincosf(0.5f * (phi + omega), &sp, &cp);
        float sm, cm; sincosf(0.5f * (phi - omega), &sm, &cm);
        g[idx * 4 + 0] = make_float2( cp * ct, -sp * ct);  // m00
        g[idx * 4 + 1] = make_float2(-cm * st, -sm * st);  // m01 = -(cm+i sm) st
        g[idx * 4 + 2] = make_float2( cm * st, -sm * st);  // m10 = (cm-i sm) st
        g[idx * 4 + 3] = make_float2( cp * ct,  sp * ct);  // m11
    }
}

// ---------------------------------------------------------------------------
// Kernel 2: one sample per 64-thread block (1 wave). State lives in LDS.
// wire w acts on bit position p = 9-w (wire 0 = MSB).
// ---------------------------------------------------------------------------
__global__ __launch_bounds__(64) void qnn_kernel(const float* __restrict__ x,
                                                 const float2* __restrict__ gmat,
                                                 float* __restrict__ out) {
    __shared__ float2 a[DIM];
    const int b    = blockIdx.x;
    const int lane = threadIdx.x;  // 0..63

    // ---- per-sample RX angles: c_p = cos(pi*x/2), s_p = sin(pi*x/2),
    //      indexed by bit position p = 9-w.
    float cpv[NQ], spv[NQ];
    #pragma unroll
    for (int w = 0; w < NQ; ++w) {
        float ang = 0.5f * 3.14159265358979323846f * x[b * NQ + w];
        float s, c; sincosf(ang, &s, &c);
        cpv[9 - w] = c;
        spv[9 - w] = s;
    }

    // ---- init: product state after RX encoding.
    // a[i] = (prod over bits) * (-i)^popcount(i)
    #pragma unroll
    for (int j = 0; j < 16; ++j) {
        int i = lane + 64 * j;
        float m = 1.0f;
        #pragma unroll
        for (int p = 0; p < NQ; ++p)
            m *= ((i >> p) & 1) ? spv[p] : cpv[p];
        int k = __popc(i) & 3;            // phase (-i)^k
        float2 v;
        if      (k == 0) v = make_float2( m,  0.0f);
        else if (k == 1) v = make_float2( 0.0f, -m);
        else if (k == 2) v = make_float2(-m,  0.0f);
        else             v = make_float2( 0.0f,  m);
        a[i] = v;
    }
    __syncthreads();

    for (int l = 0; l < NL; ++l) {
        // ---- 10 Rot gates (unrolled so bit position p is compile-time)
        #pragma unroll
        for (int w = 0; w < NQ; ++w) {
            const float2* g = &gmat[(l * NQ + w) * 4];
            float2 g00 = g[0], g01 = g[1], g10 = g[2], g11 = g[3];
            const int p      = 9 - w;
            const int stride = 1 << p;
            #pragma unroll
            for (int j = 0; j < 8; ++j) {
                int t  = lane + 64 * j;                       // pair id 0..511
                int i0 = ((t >> p) << (p + 1)) | (t & (stride - 1));
                int i1 = i0 | stride;
                float2 a0 = a[i0], a1 = a[i1];
                float2 n0, n1;
                n0.x = g00.x * a0.x - g00.y * a0.y + g01.x * a1.x - g01.y * a1.y;
                n0.y = g00.x * a0.y + g00.y * a0.x + g01.x * a1.y + g01.y * a1.x;
                n1.x = g10.x * a0.x - g10.y * a0.y + g11.x * a1.x - g11.y * a1.y;
                n1.y = g10.x * a0.y + g10.y * a0.x + g11.x * a1.y + g11.y * a1.x;
                a[i0] = n0;
                a[i1] = n1;
            }
            __syncthreads();
        }

        // ---- CNOT ring composed into one permutation pass.
        // state = C_9 ... C_0 psi  =>  new[i] = old[f_0(f_1(...f_9(i)))]
        // f_w: flip bit pt if bit pc set; pc = 9-w, pt = 9-((w+r)%10).
        const int r = (l % (NQ - 1)) + 1;   // = l+1 for NL=4
        float2 reg[16];
        #pragma unroll
        for (int j = 0; j < 16; ++j) {
            int i  = lane + 64 * j;
            int jj = i;
            #pragma unroll
            for (int w = NQ - 1; w >= 0; --w) {
                int tq = w + r; if (tq >= NQ) tq -= NQ;
                int pc = 9 - w;
                int pt = 9 - tq;
                jj ^= ((jj >> pc) & 1) << pt;
            }
            reg[j] = a[jj];
        }
        __syncthreads();
        #pragma unroll
        for (int j = 0; j < 16; ++j) a[lane + 64 * j] = reg[j];
        __syncthreads();
    }

    // ---- <Z> on last wire (LSB): sum |a|^2 * (+1 if i even else -1)
    float acc = 0.0f;
    #pragma unroll
    for (int j = 0; j < 16; ++j) {
        int i = lane + 64 * j;
        float2 v = a[i];
        acc += v.x * v.x + v.y * v.y;
    }
    acc = (lane & 1) ? -acc : acc;   // i&1 == lane&1 (64*j is even)
    #pragma unroll
    for (int m = 32; m >= 1; m >>= 1)
        acc += __shfl_xor(acc, m, 64);
    if (lane == 0) out[b] = acc;
}

extern "C" void kernel_launch(void* const* d_in, const int* in_sizes, int n_in,
                              void* d_out, int out_size, void* d_ws, size_t ws_size,
                              hipStream_t stream) {
    const float* x   = (const float*)d_in[0];   // (2048, 10) float32
    const float* wts = (const float*)d_in[1];   // (4, 10, 3) float32
    float* out  = (float*)d_out;                // (2048, 1) float32
    float2* g   = (float2*)d_ws;                // 40*4 float2 = 1280 B

    rot_precompute<<<1, 64, 0, stream>>>(wts, g);

    int B = in_sizes[0] / NQ;                   // 2048
    qnn_kernel<<<B, 64, 0, stream>>>(x, g, out);
}

// Round 2
// 34.424 us; speedup vs baseline: 1.6777x; 1.6777x over previous
//
#include <hip/hip_runtime.h>
#include <math.h>

#define NQ   10
#define NL   4
#define NREG 16   // 1024 amplitudes / 64 lanes

// ---------------------------------------------------------------------------
// Compile-time GF(2) tracking of the CNOT rings.
// Invariant: stored[q] = amp[L q]  (q = physical index, bit t; j = logical).
// Gate on logical bit p pairs stored indices {q, q ^ m}, m = column p of L^-1,
// and the logical bit value at q is parity(row_p(L) & q).
// CNOT ring layer l: amp_new[j] = amp_old[P_l j], P_l = A_0 A_1 ... A_9,
// A_w = I + E(pt,pc), pc = 9-w, pt = 9-((w+r)%10), r = l+1.
// Update: L <- P_l^-1 L,  L^-1 <- L^-1 P_l.   (all rows kept as bitmasks)
// ---------------------------------------------------------------------------
struct MaskTab { int m[NL * NQ]; int d[NL * NQ]; int sgn; bool ok; };

constexpr MaskTab make_masks() {
    MaskTab t{};
    int L[NQ] = {}, Li[NQ] = {};
    for (int p = 0; p < NQ; ++p) { L[p] = 1 << p; Li[p] = 1 << p; }
    for (int l = 0; l < NL; ++l) {
        for (int w = 0; w < NQ; ++w) {
            int p = NQ - 1 - w;
            int mm = 0;
            for (int tt = 0; tt < NQ; ++tt) mm |= ((Li[tt] >> p) & 1) << tt; // col p of L^-1
            t.m[l * NQ + w] = mm;
            t.d[l * NQ + w] = L[p];                                          // row p of L
        }
        int r = (l % (NQ - 1)) + 1;
        // L <- A_9 (... (A_0 L)):  left-mult by A_w flips: row pt ^= row pc
        for (int w = 0; w < NQ; ++w) {
            int pc = NQ - 1 - w;
            int tq = w + r; if (tq >= NQ) tq -= NQ;
            int pt = NQ - 1 - tq;
            L[pt] ^= L[pc];
        }
        // Li <- ((Li A_0) A_1) ... A_9: right-mult: per row, if bit pt set, flip bit pc
        for (int w = 0; w < NQ; ++w) {
            int pc = NQ - 1 - w;
            int tq = w + r; if (tq >= NQ) tq -= NQ;
            int pt = NQ - 1 - tq;
            for (int p = 0; p < NQ; ++p)
                Li[p] ^= ((Li[p] >> pt) & 1) << pc;
        }
    }
    t.sgn = L[0];   // <Z> on logical LSB
    bool ok = true; // verify L * Li == I
    for (int p = 0; p < NQ; ++p) {
        int row = 0;
        for (int k = 0; k < NQ; ++k)
            if ((L[p] >> k) & 1) row ^= Li[k];
        if (row != (1 << p)) ok = false;
    }
    t.ok = ok;
    return t;
}

static constexpr MaskTab MK = make_masks();
static_assert(MK.ok, "GF(2) inverse check failed");

__device__ __forceinline__ float fxor(float a, unsigned s) {
    return __uint_as_float(__float_as_uint(a) ^ s);
}

// new = sc * s + pc * p, with sc=(g00x,scy), pc=(pcx,g01y) already sign-fixed.
// (Rot structure: g11 = conj(g00), g10 = -conj(g01), so bit=1 just flips the
//  signs of g00.y and g01.x — two xors instead of full coefficient selects.)
__device__ __forceinline__ float2 cmul2(float2 s, float2 p,
                                        float g00x, float scy, float pcx, float g01y) {
    float nx = s.x * g00x;
    nx = fmaf(-scy,  s.y, nx);
    nx = fmaf( pcx,  p.x, nx);
    nx = fmaf(-g01y, p.y, nx);
    float ny = s.y * g00x;
    ny = fmaf( scy,  s.x, ny);
    ny = fmaf( pcx,  p.y, ny);
    ny = fmaf( g01y, p.x, ny);
    return make_float2(nx, ny);
}

// ---------------------------------------------------------------------------
// One sample per wave. Whole state in 32 VGPRs. No LDS, no barriers.
// ---------------------------------------------------------------------------
__global__ __launch_bounds__(64) void qnn_kernel(const float* __restrict__ x,
                                                 const float* __restrict__ wts,
                                                 float* __restrict__ out) {
    const int b    = blockIdx.x;
    const int lane = threadIdx.x;

    // ---- gate coefficients: lane gi (<40) computes Rot gate gi; broadcast
    //      later via __shfl(.., gi) -> v_readlane (SGPR).
    float g00x_r = 0.f, g00y_r = 0.f, g01x_r = 0.f, g01y_r = 0.f;
    if (lane < NL * NQ) {
        float phi = wts[lane * 3 + 0];
        float th  = wts[lane * 3 + 1];
        float om  = wts[lane * 3 + 2];
        float st_, ct_; sincosf(0.5f * th, &st_, &ct_);
        float sp,  cp;  sincosf(0.5f * (phi + om), &sp, &cp);
        float sm,  cm;  sincosf(0.5f * (phi - om), &sm, &cm);
        g00x_r =  cp * ct_;  g00y_r = -sp * ct_;   // m00 = e^{-i(phi+om)/2} cos
        g01x_r = -cm * st_;  g01y_r = -sm * st_;   // m01 = -e^{+i(phi-om)/2} sin
    }

    // ---- RX encoding angles: lane w (<10) computes sincos(pi*x_w/2)
    float myc, mys;
    {
        int w = (lane < NQ) ? lane : 0;
        float ang = 0.5f * 3.14159265358979323846f * x[b * NQ + w];
        sincosf(ang, &mys, &myc);
    }
    float cpv[NQ], spv[NQ];              // indexed by bit position p = 9-w
    #pragma unroll
    for (int p = 0; p < NQ; ++p) {
        cpv[p] = __shfl(myc, NQ - 1 - p, 64);
        spv[p] = __shfl(mys, NQ - 1 - p, 64);
    }

    // ---- init: product state  a[i] = prod_p(bit? s:c) * (-i)^popc(i)
    float LP = 1.f;
    #pragma unroll
    for (int p = 0; p < 6; ++p)
        LP *= ((lane >> p) & 1) ? spv[p] : cpv[p];
    const int kl = __popc(lane);
    const int b0 = kl & 1, b1 = (kl >> 1) & 1;
    const float bx = b0 ? 0.f : (b1 ? -1.f : 1.f);    // (-i)^kl
    const float by = b0 ? (b1 ? 1.f : -1.f) : 0.f;
    const float phx[4] = { bx,  by, -bx, -by };       // (-i)^(kl+c)
    const float phy[4] = { by, -bx, -by,  bx };

    float2 st[NREG];
    #pragma unroll
    for (int j = 0; j < NREG; ++j) {
        float HP = LP;
        #pragma unroll
        for (int p = 6; p < NQ; ++p)
            HP *= ((j >> (p - 6)) & 1) ? spv[p] : cpv[p];
        const int c = __popc(j) & 3;
        st[j].x = HP * phx[c];
        st[j].y = HP * phy[c];
    }

    // ---- 40 Rot gates in stored (permuted) space; CNOT rings are free.
    #pragma unroll
    for (int l = 0; l < NL; ++l) {
        #pragma unroll
        for (int w = 0; w < NQ; ++w) {
            const int gi    = l * NQ + w;
            const int m     = MK.m[gi];
            const int d     = MK.d[gi];
            const int mreg  = (m >> 6) & 15;
            const int mlane = m & 63;
            const int dreg  = (d >> 6) & 15;
            const int dlane = d & 63;

            const float g00x = __shfl(g00x_r, gi, 64);
            const float g00y = __shfl(g00y_r, gi, 64);
            const float g01x = __shfl(g01x_r, gi, 64);
            const float g01y = __shfl(g01y_r, gi, 64);

            const int bl = __popc(dlane & lane) & 1;          // lane part of bit value
            const unsigned s0 = (unsigned)bl << 31;
            const float scy0 = fxor(g00y, s0), pcx0 = fxor(g01x, s0);
            const float scy1 = fxor(g00y, s0 ^ 0x80000000u), pcx1 = fxor(g01x, s0 ^ 0x80000000u);

            #pragma unroll
            for (int j = 0; j < NREG; ++j) {
                if (mreg == 0) {
                    float2 s = st[j];
                    float2 p = s;
                    p.x = __shfl_xor(p.x, mlane, 64);
                    p.y = __shfl_xor(p.y, mlane, 64);
                    const int v = __popc(dreg & j) & 1;        // compile-time
                    st[j] = cmul2(s, p, g00x, v ? scy1 : scy0, v ? pcx1 : pcx0, g01y);
                } else if (j < (j ^ mreg)) {                   // each pair once, in place
                    const int j2 = j ^ mreg;
                    float2 sA = st[j], sB = st[j2];
                    float2 pA = sB,    pB = sA;
                    if (mlane) {
                        pA.x = __shfl_xor(pA.x, mlane, 64);
                        pA.y = __shfl_xor(pA.y, mlane, 64);
                        pB.x = __shfl_xor(pB.x, mlane, 64);
                        pB.y = __shfl_xor(pB.y, mlane, 64);
                    }
                    const int vA = __popc(dreg & j)  & 1;      // compile-time
                    const int vB = __popc(dreg & j2) & 1;
                    st[j]  = cmul2(sA, pA, g00x, vA ? scy1 : scy0, vA ? pcx1 : pcx0, g01y);
                    st[j2] = cmul2(sB, pB, g00x, vB ? scy1 : scy0, vB ? pcx1 : pcx0, g01y);
                }
            }
        }
    }

    // ---- <Z> on logical LSB: sign = (-1)^parity(sgn & q)
    const int sl = __popc(MK.sgn & 63 & lane) & 1;
    const float bsign = sl ? -1.f : 1.f;
    float acc = 0.f;
    #pragma unroll
    for (int j = 0; j < NREG; ++j) {
        float t = fmaf(st[j].x, st[j].x, st[j].y * st[j].y);
        const int cj = __popc(((MK.sgn >> 6) & 15) & j) & 1;   // compile-time
        acc = fmaf(t, cj ? -bsign : bsign, acc);
    }
    #pragma unroll
    for (int mm = 32; mm >= 1; mm >>= 1)
        acc += __shfl_xor(acc, mm, 64);
    if (lane == 0) out[b] = acc;
}

extern "C" void kernel_launch(void* const* d_in, const int* in_sizes, int n_in,
                              void* d_out, int out_size, void* d_ws, size_t ws_size,
                              hipStream_t stream) {
    (void)n_in; (void)d_ws; (void)ws_size; (void)out_size;
    const float* x   = (const float*)d_in[0];   // (2048, 10) float32
    const float* wts = (const float*)d_in[1];   // (4, 10, 3) float32
    float* out = (float*)d_out;                 // (2048, 1) float32
    int B = in_sizes[0] / NQ;                   // 2048
    qnn_kernel<<<B, 64, 0, stream>>>(x, wts, out);
}

// Round 3
// 29.789 us; speedup vs baseline: 1.9388x; 1.1556x over previous
//
#include <hip/hip_runtime.h>
#include <math.h>

#define NQ   10
#define NL   4
#define NREG 16   // 1024 amplitudes / 64 lanes

typedef float f32x2 __attribute__((ext_vector_type(2)));

// ---------------------------------------------------------------------------
// Compile-time GF(2) tracking of the CNOT rings.
// Invariant: stored[q] = amp[L q]. Gate on logical bit p pairs stored indices
// {q, q ^ m}, m = column p of L^-1; logical bit value at q = parity(row_p(L)&q).
// CNOT rings only update L / L^-1 (no data movement).
// Layer-3 pruning: observable sign(q) = parity(sgn & q) with sgn = final L[0].
// A layer-3 gate with parity(sgn & m) == 0 maps each pair to equal-sign
// partners -> commutes with the measurement and all remaining ops -> deleted.
// ---------------------------------------------------------------------------
struct MaskTab { int m[NL * NQ]; int d[NL * NQ]; bool keep[NL * NQ]; int sgn; bool ok; };

constexpr MaskTab make_masks() {
    MaskTab t{};
    int L[NQ] = {}, Li[NQ] = {};
    for (int p = 0; p < NQ; ++p) { L[p] = 1 << p; Li[p] = 1 << p; }
    for (int l = 0; l < NL; ++l) {
        for (int w = 0; w < NQ; ++w) {
            int p = NQ - 1 - w;
            int mm = 0;
            for (int tt = 0; tt < NQ; ++tt) mm |= ((Li[tt] >> p) & 1) << tt; // col p of L^-1
            t.m[l * NQ + w] = mm;
            t.d[l * NQ + w] = L[p];                                          // row p of L
        }
        int r = (l % (NQ - 1)) + 1;
        for (int w = 0; w < NQ; ++w) {           // L <- P_l^-1 L
            int pc = NQ - 1 - w;
            int tq = w + r; if (tq >= NQ) tq -= NQ;
            int pt = NQ - 1 - tq;
            L[pt] ^= L[pc];
        }
        for (int w = 0; w < NQ; ++w) {           // Li <- Li P_l
            int pc = NQ - 1 - w;
            int tq = w + r; if (tq >= NQ) tq -= NQ;
            int pt = NQ - 1 - tq;
            for (int p = 0; p < NQ; ++p)
                Li[p] ^= ((Li[p] >> pt) & 1) << pc;
        }
    }
    t.sgn = L[0];   // <Z> on logical LSB, in stored-index space
    for (int gi = 0; gi < NL * NQ; ++gi) {
        if (gi < (NL - 1) * NQ) { t.keep[gi] = true; continue; }
        t.keep[gi] = (__builtin_popcount((unsigned)(t.sgn & t.m[gi])) & 1) != 0;
    }
    bool ok = true; // verify L * Li == I
    for (int p = 0; p < NQ; ++p) {
        int row = 0;
        for (int k = 0; k < NQ; ++k)
            if ((L[p] >> k) & 1) row ^= Li[k];
        if (row != (1 << p)) ok = false;
    }
    t.ok = ok;
    return t;
}

static constexpr MaskTab MK = make_masks();
static_assert(MK.ok, "GF(2) inverse check failed");

__device__ __forceinline__ float fxor(float a, unsigned s) {
    return __uint_as_float(__float_as_uint(a) ^ s);
}
__device__ __forceinline__ f32x2 bc2(float v) { f32x2 r; r.x = v; r.y = v; return r; }

// n = sc*s + pc*p with sc=(g00x, scy), pc=(pcx, g01y) sign-prefixed.
// Written as packed-f32 vector math so the compiler can emit v_pk_fma_f32
// (per-half neg via modifiers): n = g00x*s + scy*(-s.y,s.x) + pcx*p + g01y*(-p.y,p.x)
__device__ __forceinline__ f32x2 cmul2v(f32x2 s, f32x2 p,
                                        float g00x, float scy, float pcx, float g01y) {
    f32x2 sswap; sswap.x = -s.y; sswap.y = s.x;
    f32x2 pswap; pswap.x = -p.y; pswap.y = p.x;
    f32x2 n = s * bc2(g00x);
    n += sswap * bc2(scy);
    n += p * bc2(pcx);
    n += pswap * bc2(g01y);
    return n;
}

// ---------------------------------------------------------------------------
// One sample per wave. Whole state in 32 VGPRs. No LDS, no barriers.
// ---------------------------------------------------------------------------
__global__ __launch_bounds__(64) void qnn_kernel(const float* __restrict__ x,
                                                 const float* __restrict__ wts,
                                                 float* __restrict__ out) {
    const int b    = blockIdx.x;
    const int lane = threadIdx.x;

    // ---- gate coefficients: lane gi (<40) computes Rot gate gi; broadcast
    //      later via __shfl(.., gi) -> readlane.
    float g00x_r = 0.f, g00y_r = 0.f, g01x_r = 0.f, g01y_r = 0.f;
    if (lane < NL * NQ) {
        float phi = wts[lane * 3 + 0];
        float th  = wts[lane * 3 + 1];
        float om  = wts[lane * 3 + 2];
        float st_, ct_; sincosf(0.5f * th, &st_, &ct_);
        float sp,  cp;  sincosf(0.5f * (phi + om), &sp, &cp);
        float sm,  cm;  sincosf(0.5f * (phi - om), &sm, &cm);
        g00x_r =  cp * ct_;  g00y_r = -sp * ct_;   // m00 = e^{-i(phi+om)/2} cos
        g01x_r = -cm * st_;  g01y_r = -sm * st_;   // m01 = -e^{+i(phi-om)/2} sin
    }

    // ---- RX encoding angles: lane w (<10) computes sincos(pi*x_w/2)
    float myc, mys;
    {
        int w = (lane < NQ) ? lane : 0;
        float ang = 0.5f * 3.14159265358979323846f * x[b * NQ + w];
        sincosf(ang, &mys, &myc);
    }
    float cpv[NQ], spv[NQ];              // indexed by bit position p = 9-w
    #pragma unroll
    for (int p = 0; p < NQ; ++p) {
        cpv[p] = __shfl(myc, NQ - 1 - p, 64);
        spv[p] = __shfl(mys, NQ - 1 - p, 64);
    }

    // ---- init: product state  a[i] = prod_p(bit? s:c) * (-i)^popc(i)
    float LP = 1.f;
    #pragma unroll
    for (int p = 0; p < 6; ++p)
        LP *= ((lane >> p) & 1) ? spv[p] : cpv[p];
    const int kl = __popc(lane);
    const int b0 = kl & 1, b1 = (kl >> 1) & 1;
    const float bx = b0 ? 0.f : (b1 ? -1.f : 1.f);    // (-i)^kl
    const float by = b0 ? (b1 ? 1.f : -1.f) : 0.f;
    const float phx[4] = { bx,  by, -bx, -by };       // (-i)^(kl+c)
    const float phy[4] = { by, -bx, -by,  bx };

    f32x2 st[NREG];
    #pragma unroll
    for (int j = 0; j < NREG; ++j) {
        float HP = LP;
        #pragma unroll
        for (int p = 6; p < NQ; ++p)
            HP *= ((j >> (p - 6)) & 1) ? spv[p] : cpv[p];
        const int c = __popc(j) & 3;
        st[j].x = HP * phx[c];
        st[j].y = HP * phy[c];
    }

    // ---- Rot gates in stored (permuted) space; CNOT rings are free.
    //      Layer-3 gates commuting with the observable are compile-time deleted.
    #pragma unroll
    for (int l = 0; l < NL; ++l) {
        #pragma unroll
        for (int w = 0; w < NQ; ++w) {
            const int gi = l * NQ + w;
            if (!MK.keep[gi]) continue;
            const int m     = MK.m[gi];
            const int d     = MK.d[gi];
            const int mreg  = (m >> 6) & 15;
            const int mlane = m & 63;
            const int dreg  = (d >> 6) & 15;
            const int dlane = d & 63;

            const float g00x = __shfl(g00x_r, gi, 64);
            const float g00y = __shfl(g00y_r, gi, 64);
            const float g01x = __shfl(g01x_r, gi, 64);
            const float g01y = __shfl(g01y_r, gi, 64);

            const int bl = __popc(dlane & lane) & 1;          // lane part of bit value
            const unsigned s0 = (unsigned)bl << 31;
            const float scy0 = fxor(g00y, s0), pcx0 = fxor(g01x, s0);
            const float scy1 = fxor(g00y, s0 ^ 0x80000000u), pcx1 = fxor(g01x, s0 ^ 0x80000000u);

            #pragma unroll
            for (int j = 0; j < NREG; ++j) {
                if (mreg == 0) {
                    f32x2 s = st[j];
                    f32x2 p = s;
                    p.x = __shfl_xor(p.x, mlane, 64);
                    p.y = __shfl_xor(p.y, mlane, 64);
                    const int v = __popc(dreg & j) & 1;        // compile-time
                    st[j] = cmul2v(s, p, g00x, v ? scy1 : scy0, v ? pcx1 : pcx0, g01y);
                } else if (j < (j ^ mreg)) {                   // each pair once, in place
                    const int j2 = j ^ mreg;
                    f32x2 sA = st[j], sB = st[j2];
                    f32x2 pA = sB,    pB = sA;
                    if (mlane) {
                        pA.x = __shfl_xor(pA.x, mlane, 64);
                        pA.y = __shfl_xor(pA.y, mlane, 64);
                        pB.x = __shfl_xor(pB.x, mlane, 64);
                        pB.y = __shfl_xor(pB.y, mlane, 64);
                    }
                    const int vA = __popc(dreg & j)  & 1;      // compile-time
                    const int vB = __popc(dreg & j2) & 1;
                    st[j]  = cmul2v(sA, pA, g00x, vA ? scy1 : scy0, vA ? pcx1 : pcx0, g01y);
                    st[j2] = cmul2v(sB, pB, g00x, vB ? scy1 : scy0, vB ? pcx1 : pcx0, g01y);
                }
            }
        }
    }

    // ---- <Z>: sign(q) = (-1)^parity(sgn & q)
    const int sl = __popc(MK.sgn & 63 & lane) & 1;
    const float bsign = sl ? -1.f : 1.f;
    float acc = 0.f;
    #pragma unroll
    for (int j = 0; j < NREG; ++j) {
        float t = fmaf(st[j].x, st[j].x, st[j].y * st[j].y);
        const int cj = __popc(((MK.sgn >> 6) & 15) & j) & 1;   // compile-time
        acc = fmaf(t, cj ? -bsign : bsign, acc);
    }
    #pragma unroll
    for (int mm = 32; mm >= 1; mm >>= 1)
        acc += __shfl_xor(acc, mm, 64);
    if (lane == 0) out[b] = acc;
}

extern "C" void kernel_launch(void* const* d_in, const int* in_sizes, int n_in,
                              void* d_out, int out_size, void* d_ws, size_t ws_size,
                              hipStream_t stream) {
    (void)n_in; (void)d_ws; (void)ws_size; (void)out_size;
    const float* x   = (const float*)d_in[0];   // (2048, 10) float32
    const float* wts = (const float*)d_in[1];   // (4, 10, 3) float32
    float* out = (float*)d_out;                 // (2048, 1) float32
    int B = in_sizes[0] / NQ;                   // 2048
    qnn_kernel<<<B, 64, 0, stream>>>(x, wts, out);
}